// Round 1
// baseline (121.327 us; speedup 1.0000x reference)
//
#include <hip/hip_runtime.h>
#include <math.h>

#define B 4
#define DEC 256
#define ENC 256
#define HDIM 512

// exp2(x*TANH_SCALE) == e^{2x};  tanh(x) = 1 - 2/(1+e^{2x})
#define TANH_SCALE 2.8853900817779268f
#define LOG2E 1.4426950408889634f

__device__ __forceinline__ float fast_exp2(float x) { return __builtin_amdgcn_exp2f(x); }
__device__ __forceinline__ float fast_rcp(float x)  { return __builtin_amdgcn_rcpf(x); }

typedef __attribute__((ext_vector_type(8))) short bf16x8;   // 8 bf16 = 4 VGPR
typedef __attribute__((ext_vector_type(4))) short bf16x4;
typedef __attribute__((ext_vector_type(4))) float f32x4;

__device__ __forceinline__ unsigned short bf16_rne(float x) {
    unsigned u = __float_as_uint(x);
    return (unsigned short)((u + 0x7FFFu + ((u >> 16) & 1u)) >> 16);
}
__device__ __forceinline__ float bf16_to_f(unsigned short h) {
    return __uint_as_float((unsigned)h << 16);
}

// Blocked-transpose W layout (shorts): ofs(m,k) = (m/16)*8192 + (k/8)*128 + (m%16)*8 + k%8
#define W_OFS(m, k) ((((long)(m) >> 4) << 13) + (((long)(k) >> 3) << 7) + (((m) & 15) << 3) + ((k) & 7))

// ---------------------------------------------------------------------------
// convert: fp32 -> bf16 hi/lo split. (unchanged)
// ---------------------------------------------------------------------------
__global__ __launch_bounds__(256) void convert_kernel(
    const float* __restrict__ enc, const float* __restrict__ dec,
    const float* __restrict__ Wmlp,
    unsigned short* __restrict__ Xh_e, unsigned short* __restrict__ Xl_e,
    unsigned short* __restrict__ Xh_d, unsigned short* __restrict__ Xl_d,
    unsigned short* __restrict__ Wh_e, unsigned short* __restrict__ Wl_e,
    unsigned short* __restrict__ Wh_d, unsigned short* __restrict__ Wl_d)
{
    const int tid = threadIdx.x, z = blockIdx.z;
    if (z < 2) {
        const float* X = z ? dec : enc;
        unsigned short* H = z ? Xh_d : Xh_e;
        unsigned short* L = z ? Xl_d : Xl_e;
        const long i8 = ((long)blockIdx.x * 256 + tid) * 8;
        float4 v0 = *(const float4*)(X + i8);
        float4 v1 = *(const float4*)(X + i8 + 4);
        float xs[8] = {v0.x, v0.y, v0.z, v0.w, v1.x, v1.y, v1.z, v1.w};
        bf16x8 hv, lv;
#pragma unroll
        for (int j = 0; j < 8; ++j) {
            unsigned short h = bf16_rne(xs[j]);
            hv[j] = (short)h;
            lv[j] = (short)bf16_rne(xs[j] - bf16_to_f(h));
        }
        *(bf16x8*)(H + i8) = hv;
        *(bf16x8*)(L + i8) = lv;
    } else {
        const float* Wsrc = Wmlp + (z == 3 ? (long)HDIM * HDIM : 0);
        unsigned short* H = (z == 3) ? Wh_d : Wh_e;
        unsigned short* L = (z == 3) ? Wl_d : Wl_e;
        const int t = blockIdx.x * 256 + tid;     // 0..65535
        const int m = t & 511;
        const int k0 = (t >> 9) << 2;             // multiple of 4
        bf16x4 hv, lv;
#pragma unroll
        for (int j = 0; j < 4; ++j) {
            float x = Wsrc[(long)(k0 + j) * 512 + m];   // coalesced reads
            unsigned short h = bf16_rne(x);
            hv[j] = (short)h;
            lv[j] = (short)bf16_rne(x - bf16_to_f(h));
        }
        const long ofs = W_OFS(m, k0);            // 4 consecutive shorts
        *(bf16x4*)(H + ofs) = hv;
        *(bf16x4*)(L + ofs) = lv;
    }
}

// ---------------------------------------------------------------------------
// proj via MFMA (unchanged): wave = 16 r x 32 m, block = 64 r x 32 m.
// ---------------------------------------------------------------------------
__global__ __launch_bounds__(256) void proj_mfma_kernel(
    const unsigned short* __restrict__ Xh_e, const unsigned short* __restrict__ Xl_e,
    const unsigned short* __restrict__ Xh_d, const unsigned short* __restrict__ Xl_d,
    const unsigned short* __restrict__ Wh_e, const unsigned short* __restrict__ Wl_e,
    const unsigned short* __restrict__ Wh_d, const unsigned short* __restrict__ Wl_d,
    const float* __restrict__ bmlp,
    float* __restrict__ ET, float* __restrict__ Dmat)
{
    const int tid = threadIdx.x;
    const int wave = tid >> 6, lane = tid & 63;
    const int z = blockIdx.z;
    const int r0w = blockIdx.x * 64 + wave * 16;
    const int m0 = blockIdx.y * 32;
    const unsigned short* Xh = z ? Xh_d : Xh_e;
    const unsigned short* Xl = z ? Xl_d : Xl_e;
    const unsigned short* Wh = z ? Wh_d : Wh_e;
    const unsigned short* Wl = z ? Wl_d : Wl_e;

    const int col = lane & 15;
    const int quad = lane >> 4;

    const unsigned short* pah = Xh + (long)(r0w + col) * 512 + quad * 8;
    const unsigned short* pal = Xl + (long)(r0w + col) * 512 + quad * 8;
    const long bofs = ((long)(m0 >> 4) << 13) + (quad << 7) + (col << 3);
    const unsigned short* pb0h = Wh + bofs;
    const unsigned short* pb0l = Wl + bofs;
    const unsigned short* pb1h = Wh + bofs + 8192;
    const unsigned short* pb1l = Wl + bofs + 8192;

    f32x4 a0h = {0.f,0.f,0.f,0.f}, a0x = {0.f,0.f,0.f,0.f};
    f32x4 a1h = {0.f,0.f,0.f,0.f}, a1x = {0.f,0.f,0.f,0.f};

    bf16x8 Ah = *(const bf16x8*)pah,  Al = *(const bf16x8*)pal;
    bf16x8 B0h = *(const bf16x8*)pb0h, B0l = *(const bf16x8*)pb0l;
    bf16x8 B1h = *(const bf16x8*)pb1h, B1l = *(const bf16x8*)pb1l;

#pragma unroll 1
    for (int k0 = 0; k0 < 512; k0 += 32) {
        bf16x8 nAh = Ah, nAl = Al, nB0h = B0h, nB0l = B0l, nB1h = B1h, nB1l = B1l;
        if (k0 + 32 < 512) {
            nAh = *(const bf16x8*)(pah + k0 + 32);
            nAl = *(const bf16x8*)(pal + k0 + 32);
            const long ko = (long)(k0 + 32) << 4;
            nB0h = *(const bf16x8*)(pb0h + ko);
            nB0l = *(const bf16x8*)(pb0l + ko);
            nB1h = *(const bf16x8*)(pb1h + ko);
            nB1l = *(const bf16x8*)(pb1l + ko);
        }
        a0h = __builtin_amdgcn_mfma_f32_16x16x32_bf16(Ah, B0h, a0h, 0, 0, 0);
        a1h = __builtin_amdgcn_mfma_f32_16x16x32_bf16(Ah, B1h, a1h, 0, 0, 0);
        a0x = __builtin_amdgcn_mfma_f32_16x16x32_bf16(Ah, B0l, a0x, 0, 0, 0);
        a1x = __builtin_amdgcn_mfma_f32_16x16x32_bf16(Ah, B1l, a1x, 0, 0, 0);
        a0x = __builtin_amdgcn_mfma_f32_16x16x32_bf16(Al, B0h, a0x, 0, 0, 0);
        a1x = __builtin_amdgcn_mfma_f32_16x16x32_bf16(Al, B1h, a1x, 0, 0, 0);
        Ah = nAh; Al = nAl; B0h = nB0h; B0l = nB0l; B1h = nB1h; B1l = nB1l;
    }

    if (z == 0) {
        const int batch = r0w >> 8;
        const int e0 = (r0w & 255) + quad * 4;
        float* base = ET + (long)batch * HDIM * ENC;
        float4 v;
        v.x = fast_exp2((a0h[0] + a0x[0]) * TANH_SCALE);
        v.y = fast_exp2((a0h[1] + a0x[1]) * TANH_SCALE);
        v.z = fast_exp2((a0h[2] + a0x[2]) * TANH_SCALE);
        v.w = fast_exp2((a0h[3] + a0x[3]) * TANH_SCALE);
        *(float4*)&base[(long)(m0 + col) * ENC + e0] = v;
        v.x = fast_exp2((a1h[0] + a1x[0]) * TANH_SCALE);
        v.y = fast_exp2((a1h[1] + a1x[1]) * TANH_SCALE);
        v.z = fast_exp2((a1h[2] + a1x[2]) * TANH_SCALE);
        v.w = fast_exp2((a1h[3] + a1x[3]) * TANH_SCALE);
        *(float4*)&base[(long)(m0 + 16 + col) * ENC + e0] = v;
    } else {
        const float bq0 = bmlp[m0 + col];
        const float bq1 = bmlp[m0 + 16 + col];
        const int r = r0w + quad * 4;
#pragma unroll
        for (int i = 0; i < 4; ++i) {
            Dmat[(long)(r + i) * HDIM + m0 + col] =
                fast_exp2((a0h[i] + a0x[i] + bq0) * TANH_SCALE);
            Dmat[(long)(r + i) * HDIM + m0 + 16 + col] =
                fast_exp2((a1h[i] + a1x[i] + bq1) * TANH_SCALE);
        }
    }
}

// ---------------------------------------------------------------------------
// FUSED attn+softmax+context: one block = (b, 4 decoder rows).
// 512 threads: ty=tid>>8 picks m-half [ty*256, ty*256+256), e=tid&255.
// Phase 1: stage D rows (4x512) + wo into LDS.
// Phase 2: acc[r] = sum_{m in half} wo[m]*rcp(1 + E[m][e]*D[r][m]).
// Phase 3: combine halves in LDS; masks; softmax over e (shfl + LDS reduce);
//          write attn; keep probs in LDS.
// Phase 4: ctx[r][h] = sum_e p[r][e]*enc[b][e][h], thread = (r, 4 h-cols).
// Replaces attn_partial + attn_finish + context: removes part buffer (8MB RT)
// and attn re-read; 5 launches -> 3.
// grid (64, 1, 4) = 256 blocks, 8 waves/block = 2 waves/SIMD.
// ---------------------------------------------------------------------------
__global__ __launch_bounds__(512) void attn_ctx_kernel(
    const float* __restrict__ Dmat, const float* __restrict__ ET,
    const float* __restrict__ wo,
    const float* __restrict__ enc, const unsigned char* __restrict__ extm,
    float* __restrict__ attn_out, float* __restrict__ ctx)
{
    __shared__ __align__(16) float ds[4][HDIM];        // 8KB   D rows
    __shared__ __align__(16) float wos[HDIM];          // 2KB   W_out
    __shared__ __align__(16) float p2[2][4][ENC];      // 8KB   m-half partials
    __shared__ __align__(16) float as4[4][ENC];        // 4KB   final probs
    __shared__ float redm[4][4];
    __shared__ float reds[4][4];

    const int tid = threadIdx.x;
    const int b = blockIdx.z, d0 = blockIdx.x * 4;
    const long g0 = (long)b * DEC + d0;

    // ---- phase 1: stage (4 rows of Dmat are contiguous = 8KB) ----
    ((float4*)ds)[tid] = ((const float4*)(Dmat + g0 * HDIM))[tid];
    if (tid < 128) ((float4*)wos)[tid] = ((const float4*)wo)[tid];

    const int ty = tid >> 8;            // which m-half
    const int e = tid & 255;
    const float* ecol = ET + (long)b * HDIM * ENC + (long)(ty * 256) * ENC + e;

    float ev[16], nv[16];
#pragma unroll
    for (int j = 0; j < 16; ++j) ev[j] = ecol[j * ENC];
    __syncthreads();

    // ---- phase 2: 256-m reduction per thread ----
    float acc[4] = {0.f, 0.f, 0.f, 0.f};
    for (int m = 0; m < 256; m += 16) {
        if (m + 16 < 256) {
#pragma unroll
            for (int j = 0; j < 16; ++j) nv[j] = ecol[(m + 16 + j) * ENC];
        }
        const int mb = ty * 256 + m;
        float4 dv[4][4], wv[4];
#pragma unroll
        for (int q = 0; q < 4; ++q) {
#pragma unroll
            for (int r = 0; r < 4; ++r)
                dv[r][q] = *(const float4*)&ds[r][mb + q * 4];
            wv[q] = *(const float4*)&wos[mb + q * 4];
        }
#pragma unroll
        for (int j = 0; j < 16; ++j) {
            float w = ((const float*)&wv[j >> 2])[j & 3];
#pragma unroll
            for (int r = 0; r < 4; ++r) {
                float t = fmaf(ev[j], ((const float*)&dv[r][j >> 2])[j & 3], 1.0f);
                acc[r] = fmaf(w, fast_rcp(t), acc[r]);
            }
        }
#pragma unroll
        for (int j = 0; j < 16; ++j) ev[j] = nv[j];
    }

#pragma unroll
    for (int r = 0; r < 4; ++r) p2[ty][r][e] = acc[r];
    __syncthreads();

    // ---- phase 3: masks + softmax on waves 0-3 (ty==0) ----
    float l[4], p[4];
    const int wave = tid >> 6, lane = tid & 63;
    if (ty == 0) {
        const bool pad = (enc[((long)b * ENC + e) * HDIM] == 0.0f);
#pragma unroll
        for (int r = 0; r < 4; ++r) {
            float a = p2[0][r][e] + p2[1][r][e];
            bool xm = extm[(g0 + r) * ENC + e] != 0;
            l[r] = (pad || xm) ? -__builtin_inff() : -2.0f * a;
        }
        float mx[4] = {l[0], l[1], l[2], l[3]};
#pragma unroll
        for (int off = 32; off >= 1; off >>= 1) {
#pragma unroll
            for (int r = 0; r < 4; ++r)
                mx[r] = fmaxf(mx[r], __shfl_xor(mx[r], off, 64));
        }
        if (lane == 0) {
#pragma unroll
            for (int r = 0; r < 4; ++r) redm[wave][r] = mx[r];
        }
    }
    __syncthreads();
    if (ty == 0) {
        float s[4];
#pragma unroll
        for (int r = 0; r < 4; ++r) {
            float gm = fmaxf(fmaxf(redm[0][r], redm[1][r]),
                             fmaxf(redm[2][r], redm[3][r]));
            p[r] = fast_exp2((l[r] - gm) * LOG2E);
            s[r] = p[r];
        }
#pragma unroll
        for (int off = 32; off >= 1; off >>= 1) {
#pragma unroll
            for (int r = 0; r < 4; ++r)
                s[r] += __shfl_xor(s[r], off, 64);
        }
        if (lane == 0) {
#pragma unroll
            for (int r = 0; r < 4; ++r) reds[wave][r] = s[r];
        }
    }
    __syncthreads();
    if (ty == 0) {
#pragma unroll
        for (int r = 0; r < 4; ++r) {
            float gs = reds[0][r] + reds[1][r] + reds[2][r] + reds[3][r];
            float pr = p[r] * fast_rcp(gs);
            attn_out[(g0 + r) * ENC + e] = pr;
            as4[r][e] = pr;
        }
    }
    __syncthreads();

    // ---- phase 4: context GEMV. thread = (row r, 4 h-cols) ----
    const int r = tid >> 7;                 // 0..3
    const int hh = (tid & 127) * 4;         // 0..508
    const float* ew = enc + (long)b * ENC * HDIM + hh;
    float4 acc4 = {0.f, 0.f, 0.f, 0.f};
    float4 wa[4], wb[4];
#pragma unroll
    for (int j = 0; j < 4; ++j) wa[j] = *(const float4*)(ew + (long)j * HDIM);
    for (int e0 = 0; e0 < ENC; e0 += 8) {
#pragma unroll
        for (int j = 0; j < 4; ++j)
            wb[j] = *(const float4*)(ew + (long)(e0 + 4 + j) * HDIM);
#pragma unroll
        for (int j = 0; j < 4; ++j) {
            float a = as4[r][e0 + j];
            acc4.x = fmaf(a, wa[j].x, acc4.x);
            acc4.y = fmaf(a, wa[j].y, acc4.y);
            acc4.z = fmaf(a, wa[j].z, acc4.z);
            acc4.w = fmaf(a, wa[j].w, acc4.w);
        }
        if (e0 + 8 < ENC) {
#pragma unroll
            for (int j = 0; j < 4; ++j)
                wa[j] = *(const float4*)(ew + (long)(e0 + 8 + j) * HDIM);
        }
#pragma unroll
        for (int j = 0; j < 4; ++j) {
            float a = as4[r][e0 + 4 + j];
            acc4.x = fmaf(a, wb[j].x, acc4.x);
            acc4.y = fmaf(a, wb[j].y, acc4.y);
            acc4.z = fmaf(a, wb[j].z, acc4.z);
            acc4.w = fmaf(a, wb[j].w, acc4.w);
        }
    }
    *(float4*)&ctx[(g0 + r) * HDIM + hh] = acc4;
}

// ---------------------------------------------------------------------------
extern "C" void kernel_launch(void* const* d_in, const int* in_sizes, int n_in,
                              void* d_out, int out_size, void* d_ws, size_t ws_size,
                              hipStream_t stream) {
    const float* dec = (const float*)d_in[0];
    const float* enc = (const float*)d_in[1];
    const unsigned char* extm = (const unsigned char*)d_in[2];
    const float* Wmlp = (const float*)d_in[3];
    const float* bmlp = (const float*)d_in[4];
    const float* Wout = (const float*)d_in[5];
    // d_in[6] = b_out: additive constant, cancels in softmax

    float* ctx = (float*)d_out;                    // [B, DEC, H]
    float* attn = ctx + (size_t)B * DEC * HDIM;    // [B, DEC, ENC]

    const size_t F = (size_t)B * DEC * HDIM;       // 524288
    float* ET = (float*)d_ws;                      // [B][H][ENC] fp32
    float* Dmat = ET + F;                          // [B*DEC][H] fp32
    unsigned short* Xh_e = (unsigned short*)(Dmat + F);
    unsigned short* Xl_e = Xh_e + F;
    unsigned short* Xh_d = Xl_e + F;
    unsigned short* Xl_d = Xh_d + F;
    unsigned short* Wh_e = Xl_d + F;               // blocked-T layout, 512*512
    unsigned short* Wl_e = Wh_e + HDIM * HDIM;
    unsigned short* Wh_d = Wl_e + HDIM * HDIM;
    unsigned short* Wl_d = Wh_d + HDIM * HDIM;

    convert_kernel<<<dim3(256, 1, 4), 256, 0, stream>>>(
        enc, dec, Wmlp, Xh_e, Xl_e, Xh_d, Xl_d, Wh_e, Wl_e, Wh_d, Wl_d);
    proj_mfma_kernel<<<dim3(16, 16, 2), 256, 0, stream>>>(
        Xh_e, Xl_e, Xh_d, Xl_d, Wh_e, Wl_e, Wh_d, Wl_d, bmlp, ET, Dmat);
    attn_ctx_kernel<<<dim3(DEC / 4, 1, B), 512, 0, stream>>>(
        Dmat, ET, Wout, enc, extm, attn, ctx);
}

// Round 2
// 117.985 us; speedup vs baseline: 1.0283x; 1.0283x over previous
//
#include <hip/hip_runtime.h>
#include <math.h>

#define B 4
#define DEC 256
#define ENC 256
#define HDIM 512

// exp2(x*TANH_SCALE) == e^{2x};  tanh(x) = 1 - 2/(1+e^{2x})
#define TANH_SCALE 2.8853900817779268f
#define LOG2E 1.4426950408889634f

__device__ __forceinline__ float fast_exp2(float x) { return __builtin_amdgcn_exp2f(x); }
__device__ __forceinline__ float fast_rcp(float x)  { return __builtin_amdgcn_rcpf(x); }

typedef __attribute__((ext_vector_type(8))) short bf16x8;   // 8 bf16 = 4 VGPR
typedef __attribute__((ext_vector_type(4))) short bf16x4;
typedef __attribute__((ext_vector_type(4))) float f32x4;

__device__ __forceinline__ unsigned short bf16_rne(float x) {
    unsigned u = __float_as_uint(x);
    return (unsigned short)((u + 0x7FFFu + ((u >> 16) & 1u)) >> 16);
}
__device__ __forceinline__ float bf16_to_f(unsigned short h) {
    return __uint_as_float((unsigned)h << 16);
}

// Blocked-transpose W layout (shorts): ofs(m,k) = (m/16)*8192 + (k/8)*128 + (m%16)*8 + k%8
#define W_OFS(m, k) ((((long)(m) >> 4) << 13) + (((long)(k) >> 3) << 7) + (((m) & 15) << 3) + ((k) & 7))

// ---------------------------------------------------------------------------
// convert: fp32 -> bf16 hi/lo split. (unchanged)
// ---------------------------------------------------------------------------
__global__ __launch_bounds__(256) void convert_kernel(
    const float* __restrict__ enc, const float* __restrict__ dec,
    const float* __restrict__ Wmlp,
    unsigned short* __restrict__ Xh_e, unsigned short* __restrict__ Xl_e,
    unsigned short* __restrict__ Xh_d, unsigned short* __restrict__ Xl_d,
    unsigned short* __restrict__ Wh_e, unsigned short* __restrict__ Wl_e,
    unsigned short* __restrict__ Wh_d, unsigned short* __restrict__ Wl_d)
{
    const int tid = threadIdx.x, z = blockIdx.z;
    if (z < 2) {
        const float* X = z ? dec : enc;
        unsigned short* H = z ? Xh_d : Xh_e;
        unsigned short* L = z ? Xl_d : Xl_e;
        const long i8 = ((long)blockIdx.x * 256 + tid) * 8;
        float4 v0 = *(const float4*)(X + i8);
        float4 v1 = *(const float4*)(X + i8 + 4);
        float xs[8] = {v0.x, v0.y, v0.z, v0.w, v1.x, v1.y, v1.z, v1.w};
        bf16x8 hv, lv;
#pragma unroll
        for (int j = 0; j < 8; ++j) {
            unsigned short h = bf16_rne(xs[j]);
            hv[j] = (short)h;
            lv[j] = (short)bf16_rne(xs[j] - bf16_to_f(h));
        }
        *(bf16x8*)(H + i8) = hv;
        *(bf16x8*)(L + i8) = lv;
    } else {
        const float* Wsrc = Wmlp + (z == 3 ? (long)HDIM * HDIM : 0);
        unsigned short* H = (z == 3) ? Wh_d : Wh_e;
        unsigned short* L = (z == 3) ? Wl_d : Wl_e;
        const int t = blockIdx.x * 256 + tid;     // 0..65535
        const int m = t & 511;
        const int k0 = (t >> 9) << 2;             // multiple of 4
        bf16x4 hv, lv;
#pragma unroll
        for (int j = 0; j < 4; ++j) {
            float x = Wsrc[(long)(k0 + j) * 512 + m];   // coalesced reads
            unsigned short h = bf16_rne(x);
            hv[j] = (short)h;
            lv[j] = (short)bf16_rne(x - bf16_to_f(h));
        }
        const long ofs = W_OFS(m, k0);            // 4 consecutive shorts
        *(bf16x4*)(H + ofs) = hv;
        *(bf16x4*)(L + ofs) = lv;
    }
}

// ---------------------------------------------------------------------------
// proj via MFMA (unchanged): wave = 16 r x 32 m, block = 64 r x 32 m.
// ---------------------------------------------------------------------------
__global__ __launch_bounds__(256) void proj_mfma_kernel(
    const unsigned short* __restrict__ Xh_e, const unsigned short* __restrict__ Xl_e,
    const unsigned short* __restrict__ Xh_d, const unsigned short* __restrict__ Xl_d,
    const unsigned short* __restrict__ Wh_e, const unsigned short* __restrict__ Wl_e,
    const unsigned short* __restrict__ Wh_d, const unsigned short* __restrict__ Wl_d,
    const float* __restrict__ bmlp,
    float* __restrict__ ET, float* __restrict__ Dmat)
{
    const int tid = threadIdx.x;
    const int wave = tid >> 6, lane = tid & 63;
    const int z = blockIdx.z;
    const int r0w = blockIdx.x * 64 + wave * 16;
    const int m0 = blockIdx.y * 32;
    const unsigned short* Xh = z ? Xh_d : Xh_e;
    const unsigned short* Xl = z ? Xl_d : Xl_e;
    const unsigned short* Wh = z ? Wh_d : Wh_e;
    const unsigned short* Wl = z ? Wl_d : Wl_e;

    const int col = lane & 15;
    const int quad = lane >> 4;

    const unsigned short* pah = Xh + (long)(r0w + col) * 512 + quad * 8;
    const unsigned short* pal = Xl + (long)(r0w + col) * 512 + quad * 8;
    const long bofs = ((long)(m0 >> 4) << 13) + (quad << 7) + (col << 3);
    const unsigned short* pb0h = Wh + bofs;
    const unsigned short* pb0l = Wl + bofs;
    const unsigned short* pb1h = Wh + bofs + 8192;
    const unsigned short* pb1l = Wl + bofs + 8192;

    f32x4 a0h = {0.f,0.f,0.f,0.f}, a0x = {0.f,0.f,0.f,0.f};
    f32x4 a1h = {0.f,0.f,0.f,0.f}, a1x = {0.f,0.f,0.f,0.f};

    bf16x8 Ah = *(const bf16x8*)pah,  Al = *(const bf16x8*)pal;
    bf16x8 B0h = *(const bf16x8*)pb0h, B0l = *(const bf16x8*)pb0l;
    bf16x8 B1h = *(const bf16x8*)pb1h, B1l = *(const bf16x8*)pb1l;

#pragma unroll 1
    for (int k0 = 0; k0 < 512; k0 += 32) {
        bf16x8 nAh = Ah, nAl = Al, nB0h = B0h, nB0l = B0l, nB1h = B1h, nB1l = B1l;
        if (k0 + 32 < 512) {
            nAh = *(const bf16x8*)(pah + k0 + 32);
            nAl = *(const bf16x8*)(pal + k0 + 32);
            const long ko = (long)(k0 + 32) << 4;
            nB0h = *(const bf16x8*)(pb0h + ko);
            nB0l = *(const bf16x8*)(pb0l + ko);
            nB1h = *(const bf16x8*)(pb1h + ko);
            nB1l = *(const bf16x8*)(pb1l + ko);
        }
        a0h = __builtin_amdgcn_mfma_f32_16x16x32_bf16(Ah, B0h, a0h, 0, 0, 0);
        a1h = __builtin_amdgcn_mfma_f32_16x16x32_bf16(Ah, B1h, a1h, 0, 0, 0);
        a0x = __builtin_amdgcn_mfma_f32_16x16x32_bf16(Ah, B0l, a0x, 0, 0, 0);
        a1x = __builtin_amdgcn_mfma_f32_16x16x32_bf16(Ah, B1l, a1x, 0, 0, 0);
        a0x = __builtin_amdgcn_mfma_f32_16x16x32_bf16(Al, B0h, a0x, 0, 0, 0);
        a1x = __builtin_amdgcn_mfma_f32_16x16x32_bf16(Al, B1h, a1x, 0, 0, 0);
        Ah = nAh; Al = nAl; B0h = nB0h; B0l = nB0l; B1h = nB1h; B1l = nB1l;
    }

    if (z == 0) {
        const int batch = r0w >> 8;
        const int e0 = (r0w & 255) + quad * 4;
        float* base = ET + (long)batch * HDIM * ENC;
        float4 v;
        v.x = fast_exp2((a0h[0] + a0x[0]) * TANH_SCALE);
        v.y = fast_exp2((a0h[1] + a0x[1]) * TANH_SCALE);
        v.z = fast_exp2((a0h[2] + a0x[2]) * TANH_SCALE);
        v.w = fast_exp2((a0h[3] + a0x[3]) * TANH_SCALE);
        *(float4*)&base[(long)(m0 + col) * ENC + e0] = v;
        v.x = fast_exp2((a1h[0] + a1x[0]) * TANH_SCALE);
        v.y = fast_exp2((a1h[1] + a1x[1]) * TANH_SCALE);
        v.z = fast_exp2((a1h[2] + a1x[2]) * TANH_SCALE);
        v.w = fast_exp2((a1h[3] + a1x[3]) * TANH_SCALE);
        *(float4*)&base[(long)(m0 + 16 + col) * ENC + e0] = v;
    } else {
        const float bq0 = bmlp[m0 + col];
        const float bq1 = bmlp[m0 + 16 + col];
        const int r = r0w + quad * 4;
#pragma unroll
        for (int i = 0; i < 4; ++i) {
            Dmat[(long)(r + i) * HDIM + m0 + col] =
                fast_exp2((a0h[i] + a0x[i] + bq0) * TANH_SCALE);
            Dmat[(long)(r + i) * HDIM + m0 + 16 + col] =
                fast_exp2((a1h[i] + a1x[i] + bq1) * TANH_SCALE);
        }
    }
}

// ---------------------------------------------------------------------------
// FUSED attn+softmax+context: one block = (b, 4 decoder rows).
// Phases 1-3 as R1.  Phase 4 REWORKED: thread = h (512 thr = 512 h), each
// thread accumulates ALL 4 rows -> enc[b] read ONCE per block (512KB, was
// 2MB: the 4x r-duplication was ~15us of L2 serialization, the round-1
// regression driver).  Probs stored transposed in LDS as4T[e][4] so one
// broadcast b128 per e yields all 4 row-probs.
// grid (64, 1, 4) = 256 blocks, 8 waves/block.
// ---------------------------------------------------------------------------
__global__ __launch_bounds__(512) void attn_ctx_kernel(
    const float* __restrict__ Dmat, const float* __restrict__ ET,
    const float* __restrict__ wo,
    const float* __restrict__ enc, const unsigned char* __restrict__ extm,
    float* __restrict__ attn_out, float* __restrict__ ctx)
{
    __shared__ __align__(16) float ds[4][HDIM];        // 8KB   D rows
    __shared__ __align__(16) float wos[HDIM];          // 2KB   W_out
    __shared__ __align__(16) float p2[2][4][ENC];      // 8KB   m-half partials
    __shared__ __align__(16) float as4T[ENC][4];       // 4KB   probs, transposed
    __shared__ float redm[4][4];
    __shared__ float reds[4][4];

    const int tid = threadIdx.x;
    const int b = blockIdx.z, d0 = blockIdx.x * 4;
    const long g0 = (long)b * DEC + d0;

    // ---- phase 1: stage (4 rows of Dmat are contiguous = 8KB) ----
    ((float4*)ds)[tid] = ((const float4*)(Dmat + g0 * HDIM))[tid];
    if (tid < 128) ((float4*)wos)[tid] = ((const float4*)wo)[tid];

    const int ty = tid >> 8;            // which m-half
    const int e = tid & 255;
    const float* ecol = ET + (long)b * HDIM * ENC + (long)(ty * 256) * ENC + e;

    float ev[16], nv[16];
#pragma unroll
    for (int j = 0; j < 16; ++j) ev[j] = ecol[j * ENC];
    __syncthreads();

    // ---- phase 2: 256-m reduction per thread ----
    float acc[4] = {0.f, 0.f, 0.f, 0.f};
    for (int m = 0; m < 256; m += 16) {
        if (m + 16 < 256) {
#pragma unroll
            for (int j = 0; j < 16; ++j) nv[j] = ecol[(m + 16 + j) * ENC];
        }
        const int mb = ty * 256 + m;
        float4 dv[4][4], wv[4];
#pragma unroll
        for (int q = 0; q < 4; ++q) {
#pragma unroll
            for (int r = 0; r < 4; ++r)
                dv[r][q] = *(const float4*)&ds[r][mb + q * 4];
            wv[q] = *(const float4*)&wos[mb + q * 4];
        }
#pragma unroll
        for (int j = 0; j < 16; ++j) {
            float w = ((const float*)&wv[j >> 2])[j & 3];
#pragma unroll
            for (int r = 0; r < 4; ++r) {
                float t = fmaf(ev[j], ((const float*)&dv[r][j >> 2])[j & 3], 1.0f);
                acc[r] = fmaf(w, fast_rcp(t), acc[r]);
            }
        }
#pragma unroll
        for (int j = 0; j < 16; ++j) ev[j] = nv[j];
    }

#pragma unroll
    for (int r = 0; r < 4; ++r) p2[ty][r][e] = acc[r];
    __syncthreads();

    // ---- phase 3: masks + softmax on waves 0-3 (ty==0) ----
    float l[4], p[4];
    const int wave = tid >> 6, lane = tid & 63;
    if (ty == 0) {
        const bool pad = (enc[((long)b * ENC + e) * HDIM] == 0.0f);
#pragma unroll
        for (int r = 0; r < 4; ++r) {
            float a = p2[0][r][e] + p2[1][r][e];
            bool xm = extm[(g0 + r) * ENC + e] != 0;
            l[r] = (pad || xm) ? -__builtin_inff() : -2.0f * a;
        }
        float mx[4] = {l[0], l[1], l[2], l[3]};
#pragma unroll
        for (int off = 32; off >= 1; off >>= 1) {
#pragma unroll
            for (int r = 0; r < 4; ++r)
                mx[r] = fmaxf(mx[r], __shfl_xor(mx[r], off, 64));
        }
        if (lane == 0) {
#pragma unroll
            for (int r = 0; r < 4; ++r) redm[wave][r] = mx[r];
        }
    }
    __syncthreads();
    if (ty == 0) {
        float s[4];
#pragma unroll
        for (int r = 0; r < 4; ++r) {
            float gm = fmaxf(fmaxf(redm[0][r], redm[1][r]),
                             fmaxf(redm[2][r], redm[3][r]));
            p[r] = fast_exp2((l[r] - gm) * LOG2E);
            s[r] = p[r];
        }
#pragma unroll
        for (int off = 32; off >= 1; off >>= 1) {
#pragma unroll
            for (int r = 0; r < 4; ++r)
                s[r] += __shfl_xor(s[r], off, 64);
        }
        if (lane == 0) {
#pragma unroll
            for (int r = 0; r < 4; ++r) reds[wave][r] = s[r];
        }
    }
    __syncthreads();
    if (ty == 0) {
        float4 pv;
        float pr[4];
#pragma unroll
        for (int r = 0; r < 4; ++r) {
            float gs = reds[0][r] + reds[1][r] + reds[2][r] + reds[3][r];
            pr[r] = p[r] * fast_rcp(gs);
            attn_out[(g0 + r) * ENC + e] = pr[r];
        }
        pv.x = pr[0]; pv.y = pr[1]; pv.z = pr[2]; pv.w = pr[3];
        *(float4*)&as4T[e][0] = pv;
    }
    __syncthreads();

    // ---- phase 4: ctx GEMV, thread = h; enc read ONCE per block ----
    const int h = tid;                              // 0..511 = HDIM
    const float* eh = enc + (long)b * ENC * HDIM + h;
    float ac0 = 0.f, ac1 = 0.f, ac2 = 0.f, ac3 = 0.f;
    float ebuf[8], nbuf[8];
#pragma unroll
    for (int j = 0; j < 8; ++j) ebuf[j] = eh[(long)j * HDIM];
    for (int e0 = 0; e0 < ENC; e0 += 8) {
        if (e0 + 8 < ENC) {
#pragma unroll
            for (int j = 0; j < 8; ++j) nbuf[j] = eh[(long)(e0 + 8 + j) * HDIM];
        }
#pragma unroll
        for (int j = 0; j < 8; ++j) {
            float4 prv = *(const float4*)&as4T[e0 + j][0];   // broadcast b128
            float ev4 = ebuf[j];
            ac0 = fmaf(prv.x, ev4, ac0);
            ac1 = fmaf(prv.y, ev4, ac1);
            ac2 = fmaf(prv.z, ev4, ac2);
            ac3 = fmaf(prv.w, ev4, ac3);
        }
#pragma unroll
        for (int j = 0; j < 8; ++j) ebuf[j] = nbuf[j];
    }
    ctx[(g0 + 0) * HDIM + h] = ac0;
    ctx[(g0 + 1) * HDIM + h] = ac1;
    ctx[(g0 + 2) * HDIM + h] = ac2;
    ctx[(g0 + 3) * HDIM + h] = ac3;
}

// ---------------------------------------------------------------------------
extern "C" void kernel_launch(void* const* d_in, const int* in_sizes, int n_in,
                              void* d_out, int out_size, void* d_ws, size_t ws_size,
                              hipStream_t stream) {
    const float* dec = (const float*)d_in[0];
    const float* enc = (const float*)d_in[1];
    const unsigned char* extm = (const unsigned char*)d_in[2];
    const float* Wmlp = (const float*)d_in[3];
    const float* bmlp = (const float*)d_in[4];
    const float* Wout = (const float*)d_in[5];
    // d_in[6] = b_out: additive constant, cancels in softmax

    float* ctx = (float*)d_out;                    // [B, DEC, H]
    float* attn = ctx + (size_t)B * DEC * HDIM;    // [B, DEC, ENC]

    const size_t F = (size_t)B * DEC * HDIM;       // 524288
    float* ET = (float*)d_ws;                      // [B][H][ENC] fp32
    float* Dmat = ET + F;                          // [B*DEC][H] fp32
    unsigned short* Xh_e = (unsigned short*)(Dmat + F);
    unsigned short* Xl_e = Xh_e + F;
    unsigned short* Xh_d = Xl_e + F;
    unsigned short* Xl_d = Xh_d + F;
    unsigned short* Wh_e = Xl_d + F;               // blocked-T layout, 512*512
    unsigned short* Wl_e = Wh_e + HDIM * HDIM;
    unsigned short* Wh_d = Wl_e + HDIM * HDIM;
    unsigned short* Wl_d = Wh_d + HDIM * HDIM;

    convert_kernel<<<dim3(256, 1, 4), 256, 0, stream>>>(
        enc, dec, Wmlp, Xh_e, Xl_e, Xh_d, Xl_d, Wh_e, Wl_e, Wh_d, Wl_d);
    proj_mfma_kernel<<<dim3(16, 16, 2), 256, 0, stream>>>(
        Xh_e, Xl_e, Xh_d, Xl_d, Wh_e, Wl_e, Wh_d, Wl_d, bmlp, ET, Dmat);
    attn_ctx_kernel<<<dim3(DEC / 4, 1, B), 512, 0, stream>>>(
        Dmat, ET, Wout, enc, extm, attn, ctx);
}

// Round 3
// 116.145 us; speedup vs baseline: 1.0446x; 1.0158x over previous
//
#include <hip/hip_runtime.h>
#include <math.h>

#define B 4
#define DEC 256
#define ENC 256
#define HDIM 512

// exp2(x*TANH_SCALE) == e^{2x};  tanh(x) = 1 - 2/(1+e^{2x})
#define TANH_SCALE 2.8853900817779268f
#define LOG2E 1.4426950408889634f

__device__ __forceinline__ float fast_exp2(float x) { return __builtin_amdgcn_exp2f(x); }
__device__ __forceinline__ float fast_rcp(float x)  { return __builtin_amdgcn_rcpf(x); }

typedef __attribute__((ext_vector_type(8))) short bf16x8;   // 8 bf16 = 4 VGPR
typedef __attribute__((ext_vector_type(4))) short bf16x4;
typedef __attribute__((ext_vector_type(4))) float f32x4;

__device__ __forceinline__ unsigned short bf16_rne(float x) {
    unsigned u = __float_as_uint(x);
    return (unsigned short)((u + 0x7FFFu + ((u >> 16) & 1u)) >> 16);
}
__device__ __forceinline__ float bf16_to_f(unsigned short h) {
    return __uint_as_float((unsigned)h << 16);
}

// Blocked-transpose W layout (shorts): ofs(m,k) = (m/16)*8192 + (k/8)*128 + (m%16)*8 + k%8
#define W_OFS(m, k) ((((long)(m) >> 4) << 13) + (((long)(k) >> 3) << 7) + (((m) & 15) << 3) + ((k) & 7))

// ---------------------------------------------------------------------------
// convert: fp32 -> bf16 hi/lo split. (unchanged)
// ---------------------------------------------------------------------------
__global__ __launch_bounds__(256) void convert_kernel(
    const float* __restrict__ enc, const float* __restrict__ dec,
    const float* __restrict__ Wmlp,
    unsigned short* __restrict__ Xh_e, unsigned short* __restrict__ Xl_e,
    unsigned short* __restrict__ Xh_d, unsigned short* __restrict__ Xl_d,
    unsigned short* __restrict__ Wh_e, unsigned short* __restrict__ Wl_e,
    unsigned short* __restrict__ Wh_d, unsigned short* __restrict__ Wl_d)
{
    const int tid = threadIdx.x, z = blockIdx.z;
    if (z < 2) {
        const float* X = z ? dec : enc;
        unsigned short* H = z ? Xh_d : Xh_e;
        unsigned short* L = z ? Xl_d : Xl_e;
        const long i8 = ((long)blockIdx.x * 256 + tid) * 8;
        float4 v0 = *(const float4*)(X + i8);
        float4 v1 = *(const float4*)(X + i8 + 4);
        float xs[8] = {v0.x, v0.y, v0.z, v0.w, v1.x, v1.y, v1.z, v1.w};
        bf16x8 hv, lv;
#pragma unroll
        for (int j = 0; j < 8; ++j) {
            unsigned short h = bf16_rne(xs[j]);
            hv[j] = (short)h;
            lv[j] = (short)bf16_rne(xs[j] - bf16_to_f(h));
        }
        *(bf16x8*)(H + i8) = hv;
        *(bf16x8*)(L + i8) = lv;
    } else {
        const float* Wsrc = Wmlp + (z == 3 ? (long)HDIM * HDIM : 0);
        unsigned short* H = (z == 3) ? Wh_d : Wh_e;
        unsigned short* L = (z == 3) ? Wl_d : Wl_e;
        const int t = blockIdx.x * 256 + tid;     // 0..65535
        const int m = t & 511;
        const int k0 = (t >> 9) << 2;             // multiple of 4
        bf16x4 hv, lv;
#pragma unroll
        for (int j = 0; j < 4; ++j) {
            float x = Wsrc[(long)(k0 + j) * 512 + m];   // coalesced reads
            unsigned short h = bf16_rne(x);
            hv[j] = (short)h;
            lv[j] = (short)bf16_rne(x - bf16_to_f(h));
        }
        const long ofs = W_OFS(m, k0);            // 4 consecutive shorts
        *(bf16x4*)(H + ofs) = hv;
        *(bf16x4*)(L + ofs) = lv;
    }
}

// ---------------------------------------------------------------------------
// proj via MFMA (unchanged): wave = 16 r x 32 m, block = 64 r x 32 m.
// ---------------------------------------------------------------------------
__global__ __launch_bounds__(256) void proj_mfma_kernel(
    const unsigned short* __restrict__ Xh_e, const unsigned short* __restrict__ Xl_e,
    const unsigned short* __restrict__ Xh_d, const unsigned short* __restrict__ Xl_d,
    const unsigned short* __restrict__ Wh_e, const unsigned short* __restrict__ Wl_e,
    const unsigned short* __restrict__ Wh_d, const unsigned short* __restrict__ Wl_d,
    const float* __restrict__ bmlp,
    float* __restrict__ ET, float* __restrict__ Dmat)
{
    const int tid = threadIdx.x;
    const int wave = tid >> 6, lane = tid & 63;
    const int z = blockIdx.z;
    const int r0w = blockIdx.x * 64 + wave * 16;
    const int m0 = blockIdx.y * 32;
    const unsigned short* Xh = z ? Xh_d : Xh_e;
    const unsigned short* Xl = z ? Xl_d : Xl_e;
    const unsigned short* Wh = z ? Wh_d : Wh_e;
    const unsigned short* Wl = z ? Wl_d : Wl_e;

    const int col = lane & 15;
    const int quad = lane >> 4;

    const unsigned short* pah = Xh + (long)(r0w + col) * 512 + quad * 8;
    const unsigned short* pal = Xl + (long)(r0w + col) * 512 + quad * 8;
    const long bofs = ((long)(m0 >> 4) << 13) + (quad << 7) + (col << 3);
    const unsigned short* pb0h = Wh + bofs;
    const unsigned short* pb0l = Wl + bofs;
    const unsigned short* pb1h = Wh + bofs + 8192;
    const unsigned short* pb1l = Wl + bofs + 8192;

    f32x4 a0h = {0.f,0.f,0.f,0.f}, a0x = {0.f,0.f,0.f,0.f};
    f32x4 a1h = {0.f,0.f,0.f,0.f}, a1x = {0.f,0.f,0.f,0.f};

    bf16x8 Ah = *(const bf16x8*)pah,  Al = *(const bf16x8*)pal;
    bf16x8 B0h = *(const bf16x8*)pb0h, B0l = *(const bf16x8*)pb0l;
    bf16x8 B1h = *(const bf16x8*)pb1h, B1l = *(const bf16x8*)pb1l;

#pragma unroll 1
    for (int k0 = 0; k0 < 512; k0 += 32) {
        bf16x8 nAh = Ah, nAl = Al, nB0h = B0h, nB0l = B0l, nB1h = B1h, nB1l = B1l;
        if (k0 + 32 < 512) {
            nAh = *(const bf16x8*)(pah + k0 + 32);
            nAl = *(const bf16x8*)(pal + k0 + 32);
            const long ko = (long)(k0 + 32) << 4;
            nB0h = *(const bf16x8*)(pb0h + ko);
            nB0l = *(const bf16x8*)(pb0l + ko);
            nB1h = *(const bf16x8*)(pb1h + ko);
            nB1l = *(const bf16x8*)(pb1l + ko);
        }
        a0h = __builtin_amdgcn_mfma_f32_16x16x32_bf16(Ah, B0h, a0h, 0, 0, 0);
        a1h = __builtin_amdgcn_mfma_f32_16x16x32_bf16(Ah, B1h, a1h, 0, 0, 0);
        a0x = __builtin_amdgcn_mfma_f32_16x16x32_bf16(Ah, B0l, a0x, 0, 0, 0);
        a1x = __builtin_amdgcn_mfma_f32_16x16x32_bf16(Ah, B1l, a1x, 0, 0, 0);
        a0x = __builtin_amdgcn_mfma_f32_16x16x32_bf16(Al, B0h, a0x, 0, 0, 0);
        a1x = __builtin_amdgcn_mfma_f32_16x16x32_bf16(Al, B1h, a1x, 0, 0, 0);
        Ah = nAh; Al = nAl; B0h = nB0h; B0l = nB0l; B1h = nB1h; B1l = nB1l;
    }

    if (z == 0) {
        const int batch = r0w >> 8;
        const int e0 = (r0w & 255) + quad * 4;
        float* base = ET + (long)batch * HDIM * ENC;
        float4 v;
        v.x = fast_exp2((a0h[0] + a0x[0]) * TANH_SCALE);
        v.y = fast_exp2((a0h[1] + a0x[1]) * TANH_SCALE);
        v.z = fast_exp2((a0h[2] + a0x[2]) * TANH_SCALE);
        v.w = fast_exp2((a0h[3] + a0x[3]) * TANH_SCALE);
        *(float4*)&base[(long)(m0 + col) * ENC + e0] = v;
        v.x = fast_exp2((a1h[0] + a1x[0]) * TANH_SCALE);
        v.y = fast_exp2((a1h[1] + a1x[1]) * TANH_SCALE);
        v.z = fast_exp2((a1h[2] + a1x[2]) * TANH_SCALE);
        v.w = fast_exp2((a1h[3] + a1x[3]) * TANH_SCALE);
        *(float4*)&base[(long)(m0 + 16 + col) * ENC + e0] = v;
    } else {
        const float bq0 = bmlp[m0 + col];
        const float bq1 = bmlp[m0 + 16 + col];
        const int r = r0w + quad * 4;
#pragma unroll
        for (int i = 0; i < 4; ++i) {
            Dmat[(long)(r + i) * HDIM + m0 + col] =
                fast_exp2((a0h[i] + a0x[i] + bq0) * TANH_SCALE);
            Dmat[(long)(r + i) * HDIM + m0 + 16 + col] =
                fast_exp2((a1h[i] + a1x[i] + bq1) * TANH_SCALE);
        }
    }
}

// ---------------------------------------------------------------------------
// FUSED attn+softmax+context v3: one block = (b, 4 decoder rows).
// Phase 2 REMAPPED: thread = (4 consecutive e, 64-m group).  ET loads are
// float4 (16B/lane, 1KB/wave) -> 4x fewer VMEM instrs than v2's per-m dword
// loads (the latency stall behind VALUBusy=38%); 16 independent rcps per
// load for ILP.  D/wo reads become wave-uniform LDS broadcasts (m = wave id
// * 64 + i).  Partials in p8[8][4][256]; combined during phase 3, which now
// uses ALL 8 waves (2 rows each, was 4 rows on half the block).
// Phase 4 (thread = h, enc read once/block) unchanged from v2.
// grid (64, 1, 4) = 256 blocks, 8 waves/block.
// ---------------------------------------------------------------------------
__global__ __launch_bounds__(512) void attn_ctx_kernel(
    const float* __restrict__ Dmat, const float* __restrict__ ET,
    const float* __restrict__ wo,
    const float* __restrict__ enc, const unsigned char* __restrict__ extm,
    float* __restrict__ attn_out, float* __restrict__ ctx)
{
    __shared__ __align__(16) float ds[4][HDIM];        // 8KB   D rows
    __shared__ __align__(16) float wos[HDIM];          // 2KB   W_out
    __shared__ __align__(16) float p8[8][4][ENC];      // 32KB  m-group partials
    __shared__ __align__(16) float as4T[ENC][4];       // 4KB   probs, transposed
    __shared__ float redm[4][4];
    __shared__ float reds[4][4];

    const int tid = threadIdx.x;
    const int b = blockIdx.z, d0 = blockIdx.x * 4;
    const long g0 = (long)b * DEC + d0;

    // ---- phase 1: stage D rows (4x512 contiguous = 8KB) + wo ----
    ((float4*)ds)[tid] = ((const float4*)(Dmat + g0 * HDIM))[tid];
    if (tid < 128) ((float4*)wos)[tid] = ((const float4*)wo)[tid];

    const int mg = tid >> 6;          // 0..7 == wave id -> m in [mg*64, mg*64+64)
    const int e4 = (tid & 63) * 4;    // 4 consecutive e per thread
    const int mbase = mg * 64;
    const float* ep = ET + (long)b * HDIM * ENC + (long)mbase * ENC + e4;

    // prefetch depth 2 (global, independent of LDS)
    float4 E0 = *(const float4*)(ep);
    float4 E1 = *(const float4*)(ep + ENC);
    __syncthreads();

    // ---- phase 2: 64-m reduction, 4 e-cols x 4 rows per thread ----
    float acc[4][4] = {};             // [r][j]
    for (int i = 0; i < 64; i += 2) {
        float4 Ea = E0, Eb = E1;
        if (i + 2 < 64) {
            E0 = *(const float4*)(ep + (long)(i + 2) * ENC);
            E1 = *(const float4*)(ep + (long)(i + 3) * ENC);
        }
        const int m = mbase + i;
        const float w0 = wos[m], w1 = wos[m + 1];
#pragma unroll
        for (int r = 0; r < 4; ++r) {
            const float dr0 = ds[r][m];
            const float dr1 = ds[r][m + 1];
#pragma unroll
            for (int j = 0; j < 4; ++j) {
                float ea = ((const float*)&Ea)[j];
                float eb = ((const float*)&Eb)[j];
                acc[r][j] = fmaf(w0, fast_rcp(fmaf(ea, dr0, 1.0f)), acc[r][j]);
                acc[r][j] = fmaf(w1, fast_rcp(fmaf(eb, dr1, 1.0f)), acc[r][j]);
            }
        }
    }
#pragma unroll
    for (int r = 0; r < 4; ++r) {
        float4 v = make_float4(acc[r][0], acc[r][1], acc[r][2], acc[r][3]);
        *(float4*)&p8[mg][r][e4] = v;
    }
    __syncthreads();

    // ---- phase 3: combine + masks + softmax, ALL 8 waves (2 rows each) ----
    const int ty = tid >> 8;          // 0 -> rows {0,1}, 1 -> rows {2,3}
    const int e = tid & 255;
    const int wave = tid >> 6, lane = tid & 63;

    const bool pad = (enc[((long)b * ENC + e) * HDIM] == 0.0f);
    float l[2], p[2];
#pragma unroll
    for (int rl = 0; rl < 2; ++rl) {
        const int r = ty * 2 + rl;
        float a = 0.f;
#pragma unroll
        for (int q = 0; q < 8; ++q) a += p8[q][r][e];
        const bool xm = extm[(g0 + r) * ENC + e] != 0;
        l[rl] = (pad || xm) ? -__builtin_inff() : -2.0f * a;
    }
    float mx[2] = {l[0], l[1]};
#pragma unroll
    for (int off = 32; off >= 1; off >>= 1) {
#pragma unroll
        for (int rl = 0; rl < 2; ++rl)
            mx[rl] = fmaxf(mx[rl], __shfl_xor(mx[rl], off, 64));
    }
    if (lane == 0) {
        redm[ty * 2 + 0][wave & 3] = mx[0];
        redm[ty * 2 + 1][wave & 3] = mx[1];
    }
    __syncthreads();
    float s[2];
#pragma unroll
    for (int rl = 0; rl < 2; ++rl) {
        const int r = ty * 2 + rl;
        const float gm = fmaxf(fmaxf(redm[r][0], redm[r][1]),
                               fmaxf(redm[r][2], redm[r][3]));
        p[rl] = fast_exp2((l[rl] - gm) * LOG2E);
        s[rl] = p[rl];
    }
#pragma unroll
    for (int off = 32; off >= 1; off >>= 1) {
#pragma unroll
        for (int rl = 0; rl < 2; ++rl)
            s[rl] += __shfl_xor(s[rl], off, 64);
    }
    if (lane == 0) {
        reds[ty * 2 + 0][wave & 3] = s[0];
        reds[ty * 2 + 1][wave & 3] = s[1];
    }
    __syncthreads();
#pragma unroll
    for (int rl = 0; rl < 2; ++rl) {
        const int r = ty * 2 + rl;
        const float gs = reds[r][0] + reds[r][1] + reds[r][2] + reds[r][3];
        const float pr = p[rl] * fast_rcp(gs);
        attn_out[(g0 + r) * ENC + e] = pr;
        as4T[e][r] = pr;
    }
    __syncthreads();

    // ---- phase 4: ctx GEMV, thread = h; enc read ONCE per block ----
    const int h = tid;                              // 0..511 = HDIM
    const float* eh = enc + (long)b * ENC * HDIM + h;
    float ac0 = 0.f, ac1 = 0.f, ac2 = 0.f, ac3 = 0.f;
    float ebuf[8], nbuf[8];
#pragma unroll
    for (int j = 0; j < 8; ++j) ebuf[j] = eh[(long)j * HDIM];
    for (int e0 = 0; e0 < ENC; e0 += 8) {
        if (e0 + 8 < ENC) {
#pragma unroll
            for (int j = 0; j < 8; ++j) nbuf[j] = eh[(long)(e0 + 8 + j) * HDIM];
        }
#pragma unroll
        for (int j = 0; j < 8; ++j) {
            float4 prv = *(const float4*)&as4T[e0 + j][0];   // broadcast b128
            float ev4 = ebuf[j];
            ac0 = fmaf(prv.x, ev4, ac0);
            ac1 = fmaf(prv.y, ev4, ac1);
            ac2 = fmaf(prv.z, ev4, ac2);
            ac3 = fmaf(prv.w, ev4, ac3);
        }
#pragma unroll
        for (int j = 0; j < 8; ++j) ebuf[j] = nbuf[j];
    }
    ctx[(g0 + 0) * HDIM + h] = ac0;
    ctx[(g0 + 1) * HDIM + h] = ac1;
    ctx[(g0 + 2) * HDIM + h] = ac2;
    ctx[(g0 + 3) * HDIM + h] = ac3;
}

// ---------------------------------------------------------------------------
extern "C" void kernel_launch(void* const* d_in, const int* in_sizes, int n_in,
                              void* d_out, int out_size, void* d_ws, size_t ws_size,
                              hipStream_t stream) {
    const float* dec = (const float*)d_in[0];
    const float* enc = (const float*)d_in[1];
    const unsigned char* extm = (const unsigned char*)d_in[2];
    const float* Wmlp = (const float*)d_in[3];
    const float* bmlp = (const float*)d_in[4];
    const float* Wout = (const float*)d_in[5];
    // d_in[6] = b_out: additive constant, cancels in softmax

    float* ctx = (float*)d_out;                    // [B, DEC, H]
    float* attn = ctx + (size_t)B * DEC * HDIM;    // [B, DEC, ENC]

    const size_t F = (size_t)B * DEC * HDIM;       // 524288
    float* ET = (float*)d_ws;                      // [B][H][ENC] fp32
    float* Dmat = ET + F;                          // [B*DEC][H] fp32
    unsigned short* Xh_e = (unsigned short*)(Dmat + F);
    unsigned short* Xl_e = Xh_e + F;
    unsigned short* Xh_d = Xl_e + F;
    unsigned short* Xl_d = Xh_d + F;
    unsigned short* Wh_e = Xl_d + F;               // blocked-T layout, 512*512
    unsigned short* Wl_e = Wh_e + HDIM * HDIM;
    unsigned short* Wh_d = Wl_e + HDIM * HDIM;
    unsigned short* Wl_d = Wh_d + HDIM * HDIM;

    convert_kernel<<<dim3(256, 1, 4), 256, 0, stream>>>(
        enc, dec, Wmlp, Xh_e, Xl_e, Xh_d, Xl_d, Wh_e, Wl_e, Wh_d, Wl_d);
    proj_mfma_kernel<<<dim3(16, 16, 2), 256, 0, stream>>>(
        Xh_e, Xl_e, Xh_d, Xl_d, Wh_e, Wl_e, Wh_d, Wl_d, bmlp, ET, Dmat);
    attn_ctx_kernel<<<dim3(DEC / 4, 1, B), 512, 0, stream>>>(
        Dmat, ET, Wout, enc, extm, attn, ctx);
}